// Round 14
// baseline (2047.423 us; speedup 1.0000x reference)
//
#include <hip/hip_runtime.h>
#include <hip/hip_bf16.h>
#include <math.h>

typedef __hip_bfloat16 bf16;

#define B_ 16
#define L_ 2048
#define DM 256
#define DI 512
#define NH 8
#define HD 64
#define DS 64
#define CD 640
#define DIP 1160
#define XB 648
#define NP 1280
#define NL 4
#define Q_ 64
#define NCH 32
#define MROWS (B_*L_)
#define EPS_ 1e-5f
#define NIN 17
#define NSMALL 14
#define STGOFF 32
#define WIPT 28552
#define WOPT 683912
#define HMPOFF 946056
#define SLICEOFF 1011592
#define PERROW 2068

__device__ __forceinline__ float u2f(unsigned short u){ return __uint_as_float(((unsigned)u)<<16); }
__device__ __forceinline__ unsigned short f2bu(float f){ bf16 h = __float2bfloat16(f); return *(unsigned short*)&h; }
__device__ __forceinline__ float sigmoidf_(float x){ return 1.f/(1.f+expf(-x)); }
__device__ __forceinline__ float siluf_(float x){ return x*sigmoidf_(x); }
__device__ __forceinline__ float softplusf_(float x){ return (x>20.f)? x : log1pf(expf(x)); }

typedef __attribute__((ext_vector_type(8))) short short8v;
typedef __attribute__((ext_vector_type(4))) float float4v;

__device__ const int kN17[NIN] = {1507328,11776,256,1187840,10240,2560,32,32,32,2048,524288,256,256,256,1,768,3};
__device__ const int sIdx[NSMALL] = {1,2,4,5,6,7,8,9,11,12,13,14,15,16};
__device__ const int sNum[NSMALL] = {11776,256,10240,2560,32,32,32,2048,256,256,256,1,768,3};
__device__ const int sOff[NSMALL] = {0,11776,12032,22272,24832,24864,24896,24928,26976,27232,27488,27744,27748,28516};

struct PtrTab { const void* p[NIN]; };

__global__ __launch_bounds__(64) void k_sentinel(float* out, float v){
    int t = threadIdx.x;
    out[t] = (t==0) ? v : 0.f;
}

__global__ __launch_bounds__(256) void k_detect(PtrTab t, int* flags){
    int i = blockIdx.x;
    int n = kN17[i];
    int S = n < 4096 ? n : 4096;
    const unsigned short* u = (const unsigned short*)t.p[i];
    __shared__ int big, ze, zo, so;
    if (threadIdx.x == 0){ big=0; ze=0; zo=0; so=0; }
    __syncthreads();
    int lbig=0, lze=0, lzo=0, lso=0;
    for (int j=threadIdx.x; j<S; j+=256){
        unsigned short v = u[j];
        int e = (v>>7)&0xFF;
        if (e >= 131) lbig = 1;
        int isz = ((v & 0x7FFF) == 0) ? 1 : 0;
        if (j & 1){ lso++; lzo += isz; } else { lze += isz; }
    }
    if (lbig) atomicOr(&big, 1);
    atomicAdd(&ze, lze); atomicAdd(&zo, lzo); atomicAdd(&so, lso);
    __syncthreads();
    if (threadIdx.x == 0){
        int Se = S - so;
        flags[i] = (big || (so > 0 && 4*ze >= 3*Se && 4*zo <= so)) ? 1 : 0;
    }
}

__global__ __launch_bounds__(256) void k_stage(PtrTab t, const int* __restrict__ flags,
                                               float* __restrict__ stg){
    int a = blockIdx.y;
    int idx = sIdx[a];
    int n = sNum[a];
    float* dst = stg + sOff[a];
    const void* p = t.p[idx];
    if (flags[idx]){
        const float* s = (const float*)p;
        for (int j=blockIdx.x*256+threadIdx.x; j<n; j += gridDim.x*256) dst[j] = s[j];
    } else {
        const unsigned short* s = (const unsigned short*)p;
        for (int j=blockIdx.x*256+threadIdx.x; j<n; j += gridDim.x*256) dst[j] = u2f(s[j]);
    }
}

__global__ __launch_bounds__(256) void k_wip(const void* __restrict__ src,
                                             const int* __restrict__ flag,
                                             unsigned short* __restrict__ dst){
    int n = blockIdx.x, l = blockIdx.y, k = threadIdx.x;
    unsigned short b = 0;
    if (n < DIP){
        size_t si = ((size_t)l*DM + k)*DIP + n;
        if (flag[0]) b = f2bu(((const float*)src)[si]);
        else         b = ((const unsigned short*)src)[si];
    }
    dst[((size_t)l*NP + n)*DM + k] = b;
}

__global__ __launch_bounds__(256) void k_wop(const void* __restrict__ src,
                                             const int* __restrict__ flag,
                                             unsigned short* __restrict__ dst){
    int n = blockIdx.x, l = blockIdx.y;
    for (int k = threadIdx.x; k < DI; k += 256){
        size_t si = ((size_t)l*DI + k)*DM + n;
        unsigned short b;
        if (flag[0]) b = f2bu(((const float*)src)[si]);
        else         b = ((const unsigned short*)src)[si];
        dst[((size_t)l*DM + n)*DI + k] = b;
    }
}

__device__ __forceinline__ float blockSum256(float v, float* red){
    #pragma unroll
    for (int off=32; off>0; off>>=1) v += __shfl_down(v, off);
    if ((threadIdx.x & 63) == 0) red[threadIdx.x >> 6] = v;
    __syncthreads();
    float s = red[0] + red[1] + red[2] + red[3];
    __syncthreads();
    return s;
}

__global__ __launch_bounds__(256) void k_inproj(const void* __restrict__ x,
                                                const int* __restrict__ flags,
                                                size_t xoff,
                                                const float* __restrict__ w,
                                                const float* __restrict__ bias,
                                                float* __restrict__ h,
                                                unsigned short* __restrict__ hbf){
    __shared__ float xs[46];
    int row = blockIdx.x;
    int t = threadIdx.x;
    bool f32 = flags[0] != 0;
    if (t < 46){
        size_t j = xoff + (size_t)row*46 + t;
        xs[t] = f32 ? ((const float*)x)[j] : u2f(((const unsigned short*)x)[j]);
    }
    __syncthreads();
    float acc = bias[t];
    #pragma unroll 2
    for (int k=0;k<46;k++) acc += xs[k]*w[k*DM + t];
    h[(size_t)row*DM + t] = acc;
    hbf[(size_t)row*DM + t] = f2bu(acc);
}

template<int MODE>
__global__ __launch_bounds__(256) void k_mgemm(const unsigned short* __restrict__ A,
                                               const unsigned short* __restrict__ Bt,
                                               float* __restrict__ O1,
                                               unsigned short* __restrict__ O1b,
                                               unsigned short* __restrict__ O2b,
                                               unsigned short* __restrict__ O3,
                                               int K){
    __shared__ unsigned short As[128*40];
    __shared__ unsigned short Bs[128*40];
    int tid = threadIdx.x;
    int wave = tid >> 6, lane = tid & 63, quad = lane >> 4, l15 = lane & 15;
    int mbase = blockIdx.y*128, nbase = blockIdx.x*128;
    int wm = (wave & 1)*64, wn = (wave >> 1)*64;
    float4v zero4 = {0.f,0.f,0.f,0.f};
    float4v acc[4][4];
    #pragma unroll
    for (int mi=0;mi<4;mi++)
        #pragma unroll
        for (int ni=0;ni<4;ni++) acc[mi][ni] = zero4;
    for (int k0 = 0; k0 < K; k0 += 32){
        #pragma unroll
        for (int i=0;i<2;i++){
            int c = tid + i*256;
            int row = c >> 2, koff = (c & 3)*8;
            *(uint4*)&As[row*40 + koff] = *(const uint4*)&A[(size_t)(mbase+row)*K + k0 + koff];
            *(uint4*)&Bs[row*40 + koff] = *(const uint4*)&Bt[(size_t)(nbase+row)*K + k0 + koff];
        }
        __syncthreads();
        short8v af[4], bfr[4];
        #pragma unroll
        for (int mi=0;mi<4;mi++) af[mi] = *(const short8v*)&As[(wm + mi*16 + l15)*40 + quad*8];
        #pragma unroll
        for (int ni=0;ni<4;ni++) bfr[ni] = *(const short8v*)&Bs[(wn + ni*16 + l15)*40 + quad*8];
        #pragma unroll
        for (int mi=0;mi<4;mi++)
            #pragma unroll
            for (int ni=0;ni<4;ni++)
                acc[mi][ni] = __builtin_amdgcn_mfma_f32_16x16x32_bf16(af[mi], bfr[ni], acc[mi][ni], 0, 0, 0);
        __syncthreads();
    }
    #pragma unroll
    for (int mi=0;mi<4;mi++){
        #pragma unroll
        for (int ni=0;ni<4;ni++){
            int col = nbase + wn + ni*16 + l15;
            #pragma unroll
            for (int reg=0;reg<4;reg++){
                int grow = mbase + wm + mi*16 + quad*4 + reg;
                float v = acc[mi][ni][reg];
                if (MODE == 0){
                    if (col < DI) O1b[(size_t)grow*DI + col] = f2bu(v);
                    else if (col < DIP) O2b[(size_t)grow*XB + (col - DI)] = f2bu(v);
                } else {
                    float hnew = O1[(size_t)grow*DM + col] + v;
                    O1[(size_t)grow*DM + col] = hnew;
                    O3[(size_t)grow*DM + col] = f2bu(hnew);
                }
            }
        }
    }
}

__global__ __launch_bounds__(320) void k_conv(const unsigned short* __restrict__ xb,
                                              const float* __restrict__ cw,
                                              const float* __restrict__ cb,
                                              unsigned short* __restrict__ xc){
    int bl = blockIdx.x;
    int l = bl & (L_-1);
    int c = threadIdx.x*2;
    float acc0 = cb[c], acc1 = cb[c+1];
    #pragma unroll
    for (int j=0;j<4;j++){
        int l2 = l - 3 + j;
        if (l2 >= 0){
            ushort2 v = *(const ushort2*)&xb[(size_t)(bl-3+j)*XB + c];
            acc0 += u2f(v.x)*cw[c*4 + j];
            acc1 += u2f(v.y)*cw[(c+1)*4 + j];
        }
    }
    ushort2 o;
    o.x = f2bu(siluf_(acc0));
    o.y = f2bu(siluf_(acc1));
    *(ushort2*)&xc[(size_t)bl*CD + c] = o;
}

__global__ __launch_bounds__(64) void k_dtcum(const unsigned short* __restrict__ xb,
                                              const float* __restrict__ dtb,
                                              const float* __restrict__ alog,
                                              float* __restrict__ dto,
                                              float* __restrict__ cumo){
    int kk = blockIdx.x, h = blockIdx.y, b = blockIdx.z;
    int t = threadIdx.x;
    int l = kk*Q_ + t;
    float raw = u2f(xb[(size_t)(b*L_ + l)*XB + CD + h]);
    float dtv = softplusf_(raw + dtb[h]);
    float A = -expf(alog[h]);
    float s = dtv * A;
    #pragma unroll
    for (int off=1; off<64; off<<=1){
        float u = __shfl_up(s, off);
        if (t >= off) s += u;
    }
    int base = (b*NH + h)*L_ + l;
    dto[base] = dtv;
    cumo[base] = s;
}

__global__ __launch_bounds__(256) void k_passS(const unsigned short* __restrict__ xc,
                                               const float* __restrict__ dt,
                                               const float* __restrict__ cum,
                                               float* __restrict__ S){
    __shared__ unsigned short Bw[64*72];
    __shared__ unsigned short Xt[64*72];
    __shared__ float sw[64];
    int kk = blockIdx.x, h = blockIdx.y, b = blockIdx.z;
    int tid = threadIdx.x;
    int bh = b*NH + h;
    int l0 = kk*Q_;
    if (tid < 64){
        int base = bh*L_ + l0;
        float c = cum[base + tid];
        float c63 = cum[base + 63];
        sw[tid] = dt[base + tid]*expf(fminf(c63 - c, 0.f));
    }
    __syncthreads();
    int srow = tid >> 4, c0 = (tid & 15)*4;
    #pragma unroll
    for (int i=0;i<4;i++){
        int s = srow + i*16;
        size_t rowbase = (size_t)(b*L_ + l0 + s)*CD;
        ushort4 bv = *(const ushort4*)&xc[rowbase + DI + c0];
        ushort4 xv = *(const ushort4*)&xc[rowbase + h*HD + c0];
        float w = sw[s];
        Bw[(c0+0)*72 + s] = f2bu(w*u2f(bv.x));
        Bw[(c0+1)*72 + s] = f2bu(w*u2f(bv.y));
        Bw[(c0+2)*72 + s] = f2bu(w*u2f(bv.z));
        Bw[(c0+3)*72 + s] = f2bu(w*u2f(bv.w));
        Xt[(c0+0)*72 + s] = xv.x;
        Xt[(c0+1)*72 + s] = xv.y;
        Xt[(c0+2)*72 + s] = xv.z;
        Xt[(c0+3)*72 + s] = xv.w;
    }
    __syncthreads();
    int wave = tid >> 6, lane = tid & 63, quad = lane >> 4, l15 = lane & 15;
    int wn = (wave & 1)*32, wp = (wave >> 1)*32;
    float4v zero4 = {0.f,0.f,0.f,0.f};
    float4v acc[2][2];
    #pragma unroll
    for (int mi=0;mi<2;mi++)
        #pragma unroll
        for (int ni=0;ni<2;ni++) acc[mi][ni] = zero4;
    #pragma unroll
    for (int k0=0;k0<64;k0+=32){
        short8v af[2], bfr[2];
        #pragma unroll
        for (int mi=0;mi<2;mi++) af[mi] = *(const short8v*)&Bw[(wn + mi*16 + l15)*72 + k0 + quad*8];
        #pragma unroll
        for (int ni=0;ni<2;ni++) bfr[ni] = *(const short8v*)&Xt[(wp + ni*16 + l15)*72 + k0 + quad*8];
        #pragma unroll
        for (int mi=0;mi<2;mi++)
            #pragma unroll
            for (int ni=0;ni<2;ni++)
                acc[mi][ni] = __builtin_amdgcn_mfma_f32_16x16x32_bf16(af[mi], bfr[ni], acc[mi][ni], 0, 0, 0);
    }
    size_t Sbase = ((size_t)bh*NCH + kk)*4096;
    #pragma unroll
    for (int mi=0;mi<2;mi++){
        #pragma unroll
        for (int ni=0;ni<2;ni++){
            int p = wp + ni*16 + l15;
            #pragma unroll
            for (int reg=0;reg<4;reg++){
                int n = wn + mi*16 + quad*4 + reg;
                S[Sbase + n*64 + p] = acc[mi][ni][reg];
            }
        }
    }
}

__global__ __launch_bounds__(256) void k_combine(const float* __restrict__ cum,
                                                 float* __restrict__ S){
    int h = blockIdx.x, b = blockIdx.y;
    int bh = b*NH + h;
    int tid = threadIdx.x;
    float4 st[4];
    #pragma unroll
    for (int i=0;i<4;i++) st[i] = make_float4(0.f,0.f,0.f,0.f);
    size_t base0 = ((size_t)bh*NCH)*4096 + (size_t)tid*16;
    for (int k=0;k<NCH;k++){
        size_t base = base0 + (size_t)k*4096;
        float dk = expf(fminf(cum[bh*L_ + k*Q_ + 63], 0.f));
        float4 a[4];
        #pragma unroll
        for (int i=0;i<4;i++) a[i] = *(const float4*)&S[base + i*4];
        #pragma unroll
        for (int i=0;i<4;i++) *(float4*)&S[base + i*4] = st[i];
        #pragma unroll
        for (int i=0;i<4;i++){
            st[i].x = a[i].x + dk*st[i].x;
            st[i].y = a[i].y + dk*st[i].y;
            st[i].z = a[i].z + dk*st[i].z;
            st[i].w = a[i].w + dk*st[i].w;
        }
    }
}

__global__ __launch_bounds__(256) void k_finalize2(const unsigned short* __restrict__ xc,
                                                   const float* __restrict__ dt,
                                                   const float* __restrict__ cum,
                                                   const float* __restrict__ Dp,
                                                   const float* __restrict__ S,
                                                   unsigned short* __restrict__ yB){
    __shared__ unsigned short Ct[64*72];
    __shared__ unsigned short Bs[64*72];
    __shared__ unsigned short Xt[64*72];
    __shared__ unsigned short St[64*72];
    __shared__ unsigned short Ml[64*72];
    __shared__ float sdt[64], scum[64];
    int kk = blockIdx.x, h = blockIdx.y, b = blockIdx.z;
    int tid = threadIdx.x;
    int bh = b*NH + h;
    int l0 = kk*Q_;
    if (tid < 64){
        int base = bh*L_ + l0;
        sdt[tid] = dt[base + tid];
        scum[tid] = cum[base + tid];
    }
    int rr = tid >> 4, c0 = (tid & 15)*4;
    size_t Sbase = ((size_t)bh*NCH + kk)*4096;
    #pragma unroll
    for (int i=0;i<4;i++){
        int r = rr + i*16;
        size_t rowbase = (size_t)(b*L_ + l0 + r)*CD;
        *(ushort4*)&Ct[r*72 + c0] = *(const ushort4*)&xc[rowbase + DI + DS + c0];
        *(ushort4*)&Bs[r*72 + c0] = *(const ushort4*)&xc[rowbase + DI + c0];
        ushort4 xv = *(const ushort4*)&xc[rowbase + h*HD + c0];
        Xt[(c0+0)*72 + r] = xv.x;
        Xt[(c0+1)*72 + r] = xv.y;
        Xt[(c0+2)*72 + r] = xv.z;
        Xt[(c0+3)*72 + r] = xv.w;
        float4 sv = *(const float4*)&S[Sbase + r*64 + c0];
        St[(c0+0)*72 + r] = f2bu(sv.x);
        St[(c0+1)*72 + r] = f2bu(sv.y);
        St[(c0+2)*72 + r] = f2bu(sv.z);
        St[(c0+3)*72 + r] = f2bu(sv.w);
    }
    __syncthreads();
    int wave = tid >> 6, lane = tid & 63, quad = lane >> 4, l15 = lane & 15;
    int wt = (wave & 1)*32, wc = (wave >> 1)*32;
    float4v zero4 = {0.f,0.f,0.f,0.f};
    {
        float4v acc[2][2];
        #pragma unroll
        for (int mi=0;mi<2;mi++)
            #pragma unroll
            for (int ni=0;ni<2;ni++) acc[mi][ni] = zero4;
        #pragma unroll
        for (int k0=0;k0<64;k0+=32){
            short8v af[2], bfr[2];
            #pragma unroll
            for (int mi=0;mi<2;mi++) af[mi] = *(const short8v*)&Ct[(wt + mi*16 + l15)*72 + k0 + quad*8];
            #pragma unroll
            for (int ni=0;ni<2;ni++) bfr[ni] = *(const short8v*)&Bs[(wc + ni*16 + l15)*72 + k0 + quad*8];
            #pragma unroll
            for (int mi=0;mi<2;mi++)
                #pragma unroll
                for (int ni=0;ni<2;ni++)
                    acc[mi][ni] = __builtin_amdgcn_mfma_f32_16x16x32_bf16(af[mi], bfr[ni], acc[mi][ni], 0, 0, 0);
        }
        #pragma unroll
        for (int mi=0;mi<2;mi++){
            #pragma unroll
            for (int ni=0;ni<2;ni++){
                int s = wc + ni*16 + l15;
                #pragma unroll
                for (int reg=0;reg<4;reg++){
                    int t = wt + mi*16 + quad*4 + reg;
                    float m = (s <= t) ? acc[mi][ni][reg]*sdt[s]*expf(fminf(scum[t]-scum[s], 0.f)) : 0.f;
                    Ml[t*72 + s] = f2bu(m);
                }
            }
        }
    }
    __syncthreads();
    {
        float4v a1[2][2], a2[2][2];
        #pragma unroll
        for (int mi=0;mi<2;mi++)
            #pragma unroll
            for (int ni=0;ni<2;ni++){ a1[mi][ni] = zero4; a2[mi][ni] = zero4; }
        #pragma unroll
        for (int k0=0;k0<64;k0+=32){
            short8v mf[2], cf[2], xf[2], sf[2];
            #pragma unroll
            for (int mi=0;mi<2;mi++){
                mf[mi] = *(const short8v*)&Ml[(wt + mi*16 + l15)*72 + k0 + quad*8];
                cf[mi] = *(const short8v*)&Ct[(wt + mi*16 + l15)*72 + k0 + quad*8];
            }
            #pragma unroll
            for (int ni=0;ni<2;ni++){
                xf[ni] = *(const short8v*)&Xt[(wc + ni*16 + l15)*72 + k0 + quad*8];
                sf[ni] = *(const short8v*)&St[(wc + ni*16 + l15)*72 + k0 + quad*8];
            }
            #pragma unroll
            for (int mi=0;mi<2;mi++)
                #pragma unroll
                for (int ni=0;ni<2;ni++){
                    a1[mi][ni] = __builtin_amdgcn_mfma_f32_16x16x32_bf16(mf[mi], xf[ni], a1[mi][ni], 0, 0, 0);
                    a2[mi][ni] = __builtin_amdgcn_mfma_f32_16x16x32_bf16(cf[mi], sf[ni], a2[mi][ni], 0, 0, 0);
                }
        }
        float Dh = Dp[h];
        #pragma unroll
        for (int mi=0;mi<2;mi++){
            #pragma unroll
            for (int ni=0;ni<2;ni++){
                int p = wc + ni*16 + l15;
                #pragma unroll
                for (int reg=0;reg<4;reg++){
                    int t = wt + mi*16 + quad*4 + reg;
                    float e = expf(fminf(scum[t], 0.f));
                    float xval = u2f(Xt[p*72 + t]);
                    yB[(size_t)(b*L_ + l0 + t)*DI + h*HD + p] =
                        f2bu(a1[mi][ni][reg] + e*a2[mi][ni][reg] + Dh*xval);
                }
            }
        }
    }
}

__global__ __launch_bounds__(256) void k_gaterms(const unsigned short* __restrict__ z,
                                                 const float* __restrict__ rw,
                                                 const unsigned short* __restrict__ yB,
                                                 unsigned short* __restrict__ ybf){
    __shared__ float red[4];
    int row = blockIdx.x;
    int tid = threadIdx.x;
    float g[2]; float ss = 0.f;
    #pragma unroll
    for (int r=0;r<2;r++){
        int d = tid + r*256;
        float zv = u2f(z[(size_t)row*DI + d]);
        float yv = u2f(yB[(size_t)row*DI + d]);
        float gv = yv * siluf_(zv);
        g[r] = gv;
        ss += gv*gv;
    }
    float tot = blockSum256(ss, red);
    float rinv = rsqrtf(tot*(1.f/512.f) + EPS_);
    #pragma unroll
    for (int r=0;r<2;r++){
        int d = tid + r*256;
        ybf[(size_t)row*DI + d] = f2bu(g[r]*rinv*rw[d]);
    }
}

__global__ __launch_bounds__(256) void k_ln(const float* __restrict__ h,
                                            const float* __restrict__ lw,
                                            const float* __restrict__ lb,
                                            float* __restrict__ out){
    __shared__ float red[4];
    int row = blockIdx.x;
    int tid = threadIdx.x;
    float v = h[(size_t)row*DM + tid];
    float mu = blockSum256(v, red)*(1.f/256.f);
    float d = v - mu;
    float var = blockSum256(d*d, red)*(1.f/256.f);
    out[(size_t)row*DM + tid] = d*rsqrtf(var + EPS_)*lw[tid] + lb[tid];
}

__global__ __launch_bounds__(256) void k_meanl(const float* __restrict__ ln,
                                               float* __restrict__ hmp,
                                               int b0){
    int g = blockIdx.x, bl = blockIdx.y;
    int tid = threadIdx.x;
    float s = 0.f;
    for (int i=0;i<128;i++){
        int l = g*128 + i;
        s += ln[(size_t)(bl*L_ + l)*DM + tid];
    }
    hmp[((size_t)(b0+bl)*16 + g)*DM + tid] = s*(1.f/2048.f);
}

__global__ __launch_bounds__(256) void k_heads(const float* __restrict__ hmp,
                                               const float* __restrict__ dw,
                                               const float* __restrict__ db,
                                               const float* __restrict__ rw,
                                               const float* __restrict__ rb,
                                               float* __restrict__ out){
    __shared__ float red[4];
    int b = blockIdx.x;
    int tid = threadIdx.x;
    float hv = 0.f;
    #pragma unroll
    for (int g=0; g<16; g++) hv += hmp[((size_t)b*16 + g)*DM + tid];
    float s0 = hv*dw[tid];
    float s1 = hv*rw[tid*3+0];
    float s2 = hv*rw[tid*3+1];
    float s3 = hv*rw[tid*3+2];
    s0 = blockSum256(s0, red);
    s1 = blockSum256(s1, red);
    s2 = blockSum256(s2, red);
    s3 = blockSum256(s3, red);
    if (tid == 0){
        out[b] = s0 + db[0];
        out[16 + b*3 + 0] = s1 + rb[0];
        out[16 + b*3 + 1] = s2 + rb[1];
        out[16 + b*3 + 2] = s3 + rb[2];
    }
}

extern "C" void kernel_launch(void* const* d_in, const int* in_sizes, int n_in,
                              void* d_out, int out_size, void* d_ws, size_t ws_size,
                              hipStream_t stream){
    static const int expSizes[NIN] = {1507328,11776,256,1187840,10240,2560,32,32,32,2048,524288,256,256,256,1,768,3};
    float* out = (float*)d_out;

    if (n_in != NIN){
        k_sentinel<<<1,64,0,stream>>>(out, 9.0e6f);
        return;
    }
    for (int i=0;i<NIN;i++){
        if (in_sizes[i] != expSizes[i]){
            k_sentinel<<<1,64,0,stream>>>(out, (float)(i+1)*1.0e5f);
            return;
        }
    }
    size_t need16 = ((size_t)SLICEOFF + 2048ull*PERROW)*4ull;
    if (ws_size < need16){
        float mb = (float)(ws_size >> 20);
        k_sentinel<<<1,64,0,stream>>>(out, 2.0e7f + mb*131072.f);
        return;
    }

    float* ws = (float*)d_ws;
    int* flags = (int*)d_ws;
    float* stg = ws + STGOFF;
    unsigned short* ipwT = (unsigned short*)(ws + WIPT);
    unsigned short* opwT = (unsigned short*)(ws + WOPT);
    float* hmp = ws + HMPOFF;

    PtrTab pt;
    for (int i=0;i<NIN;i++) pt.p[i] = d_in[i];

    k_detect<<<NIN, 256, 0, stream>>>(pt, flags);
    k_stage<<<dim3(8, NSMALL), 256, 0, stream>>>(pt, flags, stg);
    k_wip<<<dim3(NP, NL), 256, 0, stream>>>(d_in[3], flags+3, ipwT);
    k_wop<<<dim3(DM, NL), 256, 0, stream>>>(d_in[10], flags+10, opwT);

    const float* inp_w = stg + 0;
    const float* inp_b = stg + 11776;
    const float* cw    = stg + 12032;
    const float* cb    = stg + 22272;
    const float* dtb   = stg + 24832;
    const float* alog  = stg + 24864;
    const float* Dp    = stg + 24896;
    const float* rmsw  = stg + 24928;
    const float* lnw   = stg + 26976;
    const float* lnb   = stg + 27232;
    const float* dw    = stg + 27488;
    const float* db    = stg + 27744;
    const float* rw    = stg + 27748;
    const float* rb    = stg + 28516;

    int nsl = 1;
    while (((size_t)SLICEOFF + ((size_t)MROWS/nsl)*PERROW)*4ull > ws_size) nsl <<= 1;
    const size_t R = (size_t)MROWS / nsl;
    const int SB = B_ / nsl;

    float* base = ws + SLICEOFF;
    float* hbuf = base;                                         // R*256 f32
    unsigned short* hbf  = (unsigned short*)(base + R*256);     // R*256 bf16
    unsigned short* zb   = (unsigned short*)(base + R*384);     // R*512 bf16
    unsigned short* xbb  = (unsigned short*)(base + R*640);     // R*648 bf16; y aliases
    unsigned short* ybB  = xbb;
    unsigned short* xcb  = (unsigned short*)(base + R*964);     // R*640 bf16
    float* S   = base + R*1284;                                 // R*512 f32 (also LN scratch)
    float* dt  = base + R*1796;                                 // R*8
    float* cum = base + R*1804;                                 // R*8
    unsigned short* ybf = (unsigned short*)(base + R*1812);     // R*512 bf16

    for (int sl=0; sl<nsl; sl++){
        k_inproj<<<(int)R, 256, 0, stream>>>(d_in[0], flags, (size_t)sl*R*46, inp_w, inp_b, hbuf, hbf);
        for (int li=0; li<NL; li++){
            k_mgemm<0><<<dim3(NP/128, R/128), 256, 0, stream>>>(
                hbf, ipwT + (size_t)li*NP*DM, hbuf, zb, xbb, ybf, DM);
            k_conv<<<(int)R, 320, 0, stream>>>(xbb, cw + li*CD*4, cb + li*CD, xcb);
            k_dtcum<<<dim3(NCH,NH,SB), 64, 0, stream>>>(xbb, dtb + li*NH, alog + li*NH, dt, cum);
            k_passS<<<dim3(NCH,NH,SB), 256, 0, stream>>>(xcb, dt, cum, S);
            k_combine<<<dim3(NH,SB), 256, 0, stream>>>(cum, S);
            k_finalize2<<<dim3(NCH,NH,SB), 256, 0, stream>>>(xcb, dt, cum, Dp + li*NH, S, ybB);
            k_gaterms<<<(int)R, 256, 0, stream>>>(zb, rmsw + li*DI, ybB, ybf);
            k_mgemm<1><<<dim3(DM/128, R/128), 256, 0, stream>>>(
                ybf, opwT + (size_t)li*DM*DI, hbuf, zb, xbb, hbf, DI);
        }
        k_ln<<<(int)R, 256, 0, stream>>>(hbuf, lnw, lnb, S);
        k_meanl<<<dim3(16,SB), 256, 0, stream>>>(S, hmp, sl*SB);
    }
    k_heads<<<B_, 256, 0, stream>>>(hmp, dw, db, rw, rb, out);
}

// Round 15
// 2043.298 us; speedup vs baseline: 1.0020x; 1.0020x over previous
//
#include <hip/hip_runtime.h>
#include <hip/hip_bf16.h>
#include <math.h>

typedef __hip_bfloat16 bf16;

#define B_ 16
#define L_ 2048
#define DM 256
#define DI 512
#define NH 8
#define HD 64
#define DS 64
#define CD 640
#define DIP 1160
#define XB 648
#define NP 1280
#define NL 4
#define Q_ 64
#define NCH 32
#define MROWS (B_*L_)
#define EPS_ 1e-5f
#define NIN 17
#define NSMALL 14
#define STGOFF 32
#define WIPT 28552
#define WOPT 683912
#define HMPOFF 946056
#define SLICEOFF 1011592
#define PERROW 2068

__device__ __forceinline__ float u2f(unsigned short u){ return __uint_as_float(((unsigned)u)<<16); }
__device__ __forceinline__ unsigned short f2bu(float f){ bf16 h = __float2bfloat16(f); return *(unsigned short*)&h; }
__device__ __forceinline__ float sigmoidf_(float x){ return 1.f/(1.f+expf(-x)); }
__device__ __forceinline__ float siluf_(float x){ return x*sigmoidf_(x); }
__device__ __forceinline__ float softplusf_(float x){ return (x>20.f)? x : log1pf(expf(x)); }

typedef __attribute__((ext_vector_type(8))) short short8v;
typedef __attribute__((ext_vector_type(4))) float float4v;

__device__ const int kN17[NIN] = {1507328,11776,256,1187840,10240,2560,32,32,32,2048,524288,256,256,256,1,768,3};
__device__ const int sIdx[NSMALL] = {1,2,4,5,6,7,8,9,11,12,13,14,15,16};
__device__ const int sNum[NSMALL] = {11776,256,10240,2560,32,32,32,2048,256,256,256,1,768,3};
__device__ const int sOff[NSMALL] = {0,11776,12032,22272,24832,24864,24896,24928,26976,27232,27488,27744,27748,28516};

struct PtrTab { const void* p[NIN]; };

__global__ __launch_bounds__(64) void k_sentinel(float* out, float v){
    int t = threadIdx.x;
    out[t] = (t==0) ? v : 0.f;
}

__global__ __launch_bounds__(256) void k_detect(PtrTab t, int* flags){
    int i = blockIdx.x;
    int n = kN17[i];
    int S = n < 4096 ? n : 4096;
    const unsigned short* u = (const unsigned short*)t.p[i];
    __shared__ int big, ze, zo, so;
    if (threadIdx.x == 0){ big=0; ze=0; zo=0; so=0; }
    __syncthreads();
    int lbig=0, lze=0, lzo=0, lso=0;
    for (int j=threadIdx.x; j<S; j+=256){
        unsigned short v = u[j];
        int e = (v>>7)&0xFF;
        if (e >= 131) lbig = 1;
        int isz = ((v & 0x7FFF) == 0) ? 1 : 0;
        if (j & 1){ lso++; lzo += isz; } else { lze += isz; }
    }
    if (lbig) atomicOr(&big, 1);
    atomicAdd(&ze, lze); atomicAdd(&zo, lzo); atomicAdd(&so, lso);
    __syncthreads();
    if (threadIdx.x == 0){
        int Se = S - so;
        flags[i] = (big || (so > 0 && 4*ze >= 3*Se && 4*zo <= so)) ? 1 : 0;
    }
}

__global__ __launch_bounds__(256) void k_stage(PtrTab t, const int* __restrict__ flags,
                                               float* __restrict__ stg){
    int a = blockIdx.y;
    int idx = sIdx[a];
    int n = sNum[a];
    float* dst = stg + sOff[a];
    const void* p = t.p[idx];
    if (flags[idx]){
        const float* s = (const float*)p;
        for (int j=blockIdx.x*256+threadIdx.x; j<n; j += gridDim.x*256) dst[j] = s[j];
    } else {
        const unsigned short* s = (const unsigned short*)p;
        for (int j=blockIdx.x*256+threadIdx.x; j<n; j += gridDim.x*256) dst[j] = u2f(s[j]);
    }
}

__global__ __launch_bounds__(256) void k_wip(const void* __restrict__ src,
                                             const int* __restrict__ flag,
                                             unsigned short* __restrict__ dst){
    int n = blockIdx.x, l = blockIdx.y, k = threadIdx.x;
    unsigned short b = 0;
    if (n < DIP){
        size_t si = ((size_t)l*DM + k)*DIP + n;
        if (flag[0]) b = f2bu(((const float*)src)[si]);
        else         b = ((const unsigned short*)src)[si];
    }
    dst[((size_t)l*NP + n)*DM + k] = b;
}

__global__ __launch_bounds__(256) void k_wop(const void* __restrict__ src,
                                             const int* __restrict__ flag,
                                             unsigned short* __restrict__ dst){
    int n = blockIdx.x, l = blockIdx.y;
    for (int k = threadIdx.x; k < DI; k += 256){
        size_t si = ((size_t)l*DI + k)*DM + n;
        unsigned short b;
        if (flag[0]) b = f2bu(((const float*)src)[si]);
        else         b = ((const unsigned short*)src)[si];
        dst[((size_t)l*DM + n)*DI + k] = b;
    }
}

__device__ __forceinline__ float blockSum256(float v, float* red){
    #pragma unroll
    for (int off=32; off>0; off>>=1) v += __shfl_down(v, off);
    if ((threadIdx.x & 63) == 0) red[threadIdx.x >> 6] = v;
    __syncthreads();
    float s = red[0] + red[1] + red[2] + red[3];
    __syncthreads();
    return s;
}

__global__ __launch_bounds__(256) void k_inproj(const void* __restrict__ x,
                                                const int* __restrict__ flags,
                                                size_t xoff,
                                                const float* __restrict__ w,
                                                const float* __restrict__ bias,
                                                float* __restrict__ h,
                                                unsigned short* __restrict__ hbf){
    __shared__ float xs[46];
    int row = blockIdx.x;
    int t = threadIdx.x;
    bool f32 = flags[0] != 0;
    if (t < 46){
        size_t j = xoff + (size_t)row*46 + t;
        xs[t] = f32 ? ((const float*)x)[j] : u2f(((const unsigned short*)x)[j]);
    }
    __syncthreads();
    float acc = bias[t];
    #pragma unroll 2
    for (int k=0;k<46;k++) acc += xs[k]*w[k*DM + t];
    h[(size_t)row*DM + t] = acc;
    hbf[(size_t)row*DM + t] = f2bu(acc);
}

template<int MODE>
__global__ __launch_bounds__(256) void k_mgemm(const unsigned short* __restrict__ A,
                                               const unsigned short* __restrict__ Bt,
                                               float* __restrict__ O1,
                                               unsigned short* __restrict__ O1b,
                                               unsigned short* __restrict__ O2b,
                                               unsigned short* __restrict__ O3,
                                               int K){
    __shared__ unsigned short As[128*40];
    __shared__ unsigned short Bs[128*40];
    int tid = threadIdx.x;
    int wave = tid >> 6, lane = tid & 63, quad = lane >> 4, l15 = lane & 15;
    int mbase = blockIdx.y*128, nbase = blockIdx.x*128;
    int wm = (wave & 1)*64, wn = (wave >> 1)*64;
    float4v zero4 = {0.f,0.f,0.f,0.f};
    float4v acc[4][4];
    #pragma unroll
    for (int mi=0;mi<4;mi++)
        #pragma unroll
        for (int ni=0;ni<4;ni++) acc[mi][ni] = zero4;
    for (int k0 = 0; k0 < K; k0 += 32){
        #pragma unroll
        for (int i=0;i<2;i++){
            int c = tid + i*256;
            int row = c >> 2, koff = (c & 3)*8;
            *(uint4*)&As[row*40 + koff] = *(const uint4*)&A[(size_t)(mbase+row)*K + k0 + koff];
            *(uint4*)&Bs[row*40 + koff] = *(const uint4*)&Bt[(size_t)(nbase+row)*K + k0 + koff];
        }
        __syncthreads();
        short8v af[4], bfr[4];
        #pragma unroll
        for (int mi=0;mi<4;mi++) af[mi] = *(const short8v*)&As[(wm + mi*16 + l15)*40 + quad*8];
        #pragma unroll
        for (int ni=0;ni<4;ni++) bfr[ni] = *(const short8v*)&Bs[(wn + ni*16 + l15)*40 + quad*8];
        #pragma unroll
        for (int mi=0;mi<4;mi++)
            #pragma unroll
            for (int ni=0;ni<4;ni++)
                acc[mi][ni] = __builtin_amdgcn_mfma_f32_16x16x32_bf16(af[mi], bfr[ni], acc[mi][ni], 0, 0, 0);
        __syncthreads();
    }
    #pragma unroll
    for (int mi=0;mi<4;mi++){
        #pragma unroll
        for (int ni=0;ni<4;ni++){
            int col = nbase + wn + ni*16 + l15;
            #pragma unroll
            for (int reg=0;reg<4;reg++){
                int grow = mbase + wm + mi*16 + quad*4 + reg;
                float v = acc[mi][ni][reg];
                if (MODE == 0){
                    if (col < DI) O1b[(size_t)grow*DI + col] = f2bu(v);
                    else if (col < DIP) O2b[(size_t)grow*XB + (col - DI)] = f2bu(v);
                } else {
                    float hnew = O1[(size_t)grow*DM + col] + v;
                    O1[(size_t)grow*DM + col] = hnew;
                    O3[(size_t)grow*DM + col] = f2bu(hnew);
                }
            }
        }
    }
}

// ---- conv(4)+bias+SiLU, bf16 in/out, grid-stride, ushort4/iter (high MLP) ----
__global__ __launch_bounds__(256) void k_conv(const unsigned short* __restrict__ xb,
                                              const float* __restrict__ cw,
                                              const float* __restrict__ cb,
                                              unsigned short* __restrict__ xc,
                                              int total){
    for (int u = blockIdx.x*256 + threadIdx.x; u < total; u += gridDim.x*256){
        int bl = u / 160;
        int c = (u - bl*160)*4;
        int l = bl & (L_-1);
        float a0 = cb[c], a1 = cb[c+1], a2 = cb[c+2], a3 = cb[c+3];
        #pragma unroll
        for (int j=0;j<4;j++){
            int l2 = l - 3 + j;
            if (l2 >= 0){
                ushort4 v = *(const ushort4*)&xb[(size_t)(bl-3+j)*XB + c];
                a0 += u2f(v.x)*cw[c*4 + j];
                a1 += u2f(v.y)*cw[(c+1)*4 + j];
                a2 += u2f(v.z)*cw[(c+2)*4 + j];
                a3 += u2f(v.w)*cw[(c+3)*4 + j];
            }
        }
        ushort4 o;
        o.x = f2bu(siluf_(a0));
        o.y = f2bu(siluf_(a1));
        o.z = f2bu(siluf_(a2));
        o.w = f2bu(siluf_(a3));
        *(ushort4*)&xc[(size_t)bl*CD + c] = o;
    }
}

__global__ __launch_bounds__(64) void k_dtcum(const unsigned short* __restrict__ xb,
                                              const float* __restrict__ dtb,
                                              const float* __restrict__ alog,
                                              float* __restrict__ dto,
                                              float* __restrict__ cumo){
    int kk = blockIdx.x, h = blockIdx.y, b = blockIdx.z;
    int t = threadIdx.x;
    int l = kk*Q_ + t;
    float raw = u2f(xb[(size_t)(b*L_ + l)*XB + CD + h]);
    float dtv = softplusf_(raw + dtb[h]);
    float A = -expf(alog[h]);
    float s = dtv * A;
    #pragma unroll
    for (int off=1; off<64; off<<=1){
        float u = __shfl_up(s, off);
        if (t >= off) s += u;
    }
    int base = (b*NH + h)*L_ + l;
    dto[base] = dtv;
    cumo[base] = s;
}

__global__ __launch_bounds__(256) void k_passS(const unsigned short* __restrict__ xc,
                                               const float* __restrict__ dt,
                                               const float* __restrict__ cum,
                                               float* __restrict__ S){
    __shared__ unsigned short Bw[64*72];
    __shared__ unsigned short Xt[64*72];
    __shared__ float sw[64];
    int kk = blockIdx.x, h = blockIdx.y, b = blockIdx.z;
    int tid = threadIdx.x;
    int bh = b*NH + h;
    int l0 = kk*Q_;
    if (tid < 64){
        int base = bh*L_ + l0;
        float c = cum[base + tid];
        float c63 = cum[base + 63];
        sw[tid] = dt[base + tid]*expf(fminf(c63 - c, 0.f));
    }
    __syncthreads();
    int srow = tid >> 4, c0 = (tid & 15)*4;
    #pragma unroll
    for (int i=0;i<4;i++){
        int s = srow + i*16;
        size_t rowbase = (size_t)(b*L_ + l0 + s)*CD;
        ushort4 bv = *(const ushort4*)&xc[rowbase + DI + c0];
        ushort4 xv = *(const ushort4*)&xc[rowbase + h*HD + c0];
        float w = sw[s];
        Bw[(c0+0)*72 + s] = f2bu(w*u2f(bv.x));
        Bw[(c0+1)*72 + s] = f2bu(w*u2f(bv.y));
        Bw[(c0+2)*72 + s] = f2bu(w*u2f(bv.z));
        Bw[(c0+3)*72 + s] = f2bu(w*u2f(bv.w));
        Xt[(c0+0)*72 + s] = xv.x;
        Xt[(c0+1)*72 + s] = xv.y;
        Xt[(c0+2)*72 + s] = xv.z;
        Xt[(c0+3)*72 + s] = xv.w;
    }
    __syncthreads();
    int wave = tid >> 6, lane = tid & 63, quad = lane >> 4, l15 = lane & 15;
    int wn = (wave & 1)*32, wp = (wave >> 1)*32;
    float4v zero4 = {0.f,0.f,0.f,0.f};
    float4v acc[2][2];
    #pragma unroll
    for (int mi=0;mi<2;mi++)
        #pragma unroll
        for (int ni=0;ni<2;ni++) acc[mi][ni] = zero4;
    #pragma unroll
    for (int k0=0;k0<64;k0+=32){
        short8v af[2], bfr[2];
        #pragma unroll
        for (int mi=0;mi<2;mi++) af[mi] = *(const short8v*)&Bw[(wn + mi*16 + l15)*72 + k0 + quad*8];
        #pragma unroll
        for (int ni=0;ni<2;ni++) bfr[ni] = *(const short8v*)&Xt[(wp + ni*16 + l15)*72 + k0 + quad*8];
        #pragma unroll
        for (int mi=0;mi<2;mi++)
            #pragma unroll
            for (int ni=0;ni<2;ni++)
                acc[mi][ni] = __builtin_amdgcn_mfma_f32_16x16x32_bf16(af[mi], bfr[ni], acc[mi][ni], 0, 0, 0);
    }
    size_t Sbase = ((size_t)bh*NCH + kk)*4096;
    #pragma unroll
    for (int mi=0;mi<2;mi++){
        #pragma unroll
        for (int ni=0;ni<2;ni++){
            int p = wp + ni*16 + l15;
            #pragma unroll
            for (int reg=0;reg<4;reg++){
                int n = wn + mi*16 + quad*4 + reg;
                S[Sbase + n*64 + p] = acc[mi][ni][reg];
            }
        }
    }
}

__global__ __launch_bounds__(256) void k_combine(const float* __restrict__ cum,
                                                 float* __restrict__ S){
    int h = blockIdx.x, b = blockIdx.y;
    int bh = b*NH + h;
    int tid = threadIdx.x;
    float4 st[4];
    #pragma unroll
    for (int i=0;i<4;i++) st[i] = make_float4(0.f,0.f,0.f,0.f);
    size_t base0 = ((size_t)bh*NCH)*4096 + (size_t)tid*16;
    for (int k=0;k<NCH;k++){
        size_t base = base0 + (size_t)k*4096;
        float dk = expf(fminf(cum[bh*L_ + k*Q_ + 63], 0.f));
        float4 a[4];
        #pragma unroll
        for (int i=0;i<4;i++) a[i] = *(const float4*)&S[base + i*4];
        #pragma unroll
        for (int i=0;i<4;i++) *(float4*)&S[base + i*4] = st[i];
        #pragma unroll
        for (int i=0;i<4;i++){
            st[i].x = a[i].x + dk*st[i].x;
            st[i].y = a[i].y + dk*st[i].y;
            st[i].z = a[i].z + dk*st[i].z;
            st[i].w = a[i].w + dk*st[i].w;
        }
    }
}

__global__ __launch_bounds__(256) void k_finalize2(const unsigned short* __restrict__ xc,
                                                   const float* __restrict__ dt,
                                                   const float* __restrict__ cum,
                                                   const float* __restrict__ Dp,
                                                   const float* __restrict__ S,
                                                   unsigned short* __restrict__ yB){
    __shared__ unsigned short Ct[64*72];
    __shared__ unsigned short Bs[64*72];
    __shared__ unsigned short Xt[64*72];
    __shared__ unsigned short St[64*72];
    __shared__ unsigned short Ml[64*72];
    __shared__ float sdt[64], scum[64];
    int kk = blockIdx.x, h = blockIdx.y, b = blockIdx.z;
    int tid = threadIdx.x;
    int bh = b*NH + h;
    int l0 = kk*Q_;
    if (tid < 64){
        int base = bh*L_ + l0;
        sdt[tid] = dt[base + tid];
        scum[tid] = cum[base + tid];
    }
    int rr = tid >> 4, c0 = (tid & 15)*4;
    size_t Sbase = ((size_t)bh*NCH + kk)*4096;
    #pragma unroll
    for (int i=0;i<4;i++){
        int r = rr + i*16;
        size_t rowbase = (size_t)(b*L_ + l0 + r)*CD;
        *(ushort4*)&Ct[r*72 + c0] = *(const ushort4*)&xc[rowbase + DI + DS + c0];
        *(ushort4*)&Bs[r*72 + c0] = *(const ushort4*)&xc[rowbase + DI + c0];
        ushort4 xv = *(const ushort4*)&xc[rowbase + h*HD + c0];
        Xt[(c0+0)*72 + r] = xv.x;
        Xt[(c0+1)*72 + r] = xv.y;
        Xt[(c0+2)*72 + r] = xv.z;
        Xt[(c0+3)*72 + r] = xv.w;
        float4 sv = *(const float4*)&S[Sbase + r*64 + c0];
        St[(c0+0)*72 + r] = f2bu(sv.x);
        St[(c0+1)*72 + r] = f2bu(sv.y);
        St[(c0+2)*72 + r] = f2bu(sv.z);
        St[(c0+3)*72 + r] = f2bu(sv.w);
    }
    __syncthreads();
    int wave = tid >> 6, lane = tid & 63, quad = lane >> 4, l15 = lane & 15;
    int wt = (wave & 1)*32, wc = (wave >> 1)*32;
    float4v zero4 = {0.f,0.f,0.f,0.f};
    {
        float4v acc[2][2];
        #pragma unroll
        for (int mi=0;mi<2;mi++)
            #pragma unroll
            for (int ni=0;ni<2;ni++) acc[mi][ni] = zero4;
        #pragma unroll
        for (int k0=0;k0<64;k0+=32){
            short8v af[2], bfr[2];
            #pragma unroll
            for (int mi=0;mi<2;mi++) af[mi] = *(const short8v*)&Ct[(wt + mi*16 + l15)*72 + k0 + quad*8];
            #pragma unroll
            for (int ni=0;ni<2;ni++) bfr[ni] = *(const short8v*)&Bs[(wc + ni*16 + l15)*72 + k0 + quad*8];
            #pragma unroll
            for (int mi=0;mi<2;mi++)
                #pragma unroll
                for (int ni=0;ni<2;ni++)
                    acc[mi][ni] = __builtin_amdgcn_mfma_f32_16x16x32_bf16(af[mi], bfr[ni], acc[mi][ni], 0, 0, 0);
        }
        #pragma unroll
        for (int mi=0;mi<2;mi++){
            #pragma unroll
            for (int ni=0;ni<2;ni++){
                int s = wc + ni*16 + l15;
                #pragma unroll
                for (int reg=0;reg<4;reg++){
                    int t = wt + mi*16 + quad*4 + reg;
                    float m = (s <= t) ? acc[mi][ni][reg]*sdt[s]*expf(fminf(scum[t]-scum[s], 0.f)) : 0.f;
                    Ml[t*72 + s] = f2bu(m);
                }
            }
        }
    }
    __syncthreads();
    {
        float4v a1[2][2], a2[2][2];
        #pragma unroll
        for (int mi=0;mi<2;mi++)
            #pragma unroll
            for (int ni=0;ni<2;ni++){ a1[mi][ni] = zero4; a2[mi][ni] = zero4; }
        #pragma unroll
        for (int k0=0;k0<64;k0+=32){
            short8v mf[2], cf[2], xf[2], sf[2];
            #pragma unroll
            for (int mi=0;mi<2;mi++){
                mf[mi] = *(const short8v*)&Ml[(wt + mi*16 + l15)*72 + k0 + quad*8];
                cf[mi] = *(const short8v*)&Ct[(wt + mi*16 + l15)*72 + k0 + quad*8];
            }
            #pragma unroll
            for (int ni=0;ni<2;ni++){
                xf[ni] = *(const short8v*)&Xt[(wc + ni*16 + l15)*72 + k0 + quad*8];
                sf[ni] = *(const short8v*)&St[(wc + ni*16 + l15)*72 + k0 + quad*8];
            }
            #pragma unroll
            for (int mi=0;mi<2;mi++)
                #pragma unroll
                for (int ni=0;ni<2;ni++){
                    a1[mi][ni] = __builtin_amdgcn_mfma_f32_16x16x32_bf16(mf[mi], xf[ni], a1[mi][ni], 0, 0, 0);
                    a2[mi][ni] = __builtin_amdgcn_mfma_f32_16x16x32_bf16(cf[mi], sf[ni], a2[mi][ni], 0, 0, 0);
                }
        }
        float Dh = Dp[h];
        #pragma unroll
        for (int mi=0;mi<2;mi++){
            #pragma unroll
            for (int ni=0;ni<2;ni++){
                int p = wc + ni*16 + l15;
                #pragma unroll
                for (int reg=0;reg<4;reg++){
                    int t = wt + mi*16 + quad*4 + reg;
                    float e = expf(fminf(scum[t], 0.f));
                    float xval = u2f(Xt[p*72 + t]);
                    yB[(size_t)(b*L_ + l0 + t)*DI + h*HD + p] =
                        f2bu(a1[mi][ni][reg] + e*a2[mi][ni][reg] + Dh*xval);
                }
            }
        }
    }
}

__global__ __launch_bounds__(256) void k_gaterms(const unsigned short* __restrict__ z,
                                                 const float* __restrict__ rw,
                                                 const unsigned short* __restrict__ yB,
                                                 unsigned short* __restrict__ ybf){
    __shared__ float red[4];
    int row = blockIdx.x;
    int tid = threadIdx.x;
    float g[2]; float ss = 0.f;
    #pragma unroll
    for (int r=0;r<2;r++){
        int d = tid + r*256;
        float zv = u2f(z[(size_t)row*DI + d]);
        float yv = u2f(yB[(size_t)row*DI + d]);
        float gv = yv * siluf_(zv);
        g[r] = gv;
        ss += gv*gv;
    }
    float tot = blockSum256(ss, red);
    float rinv = rsqrtf(tot*(1.f/512.f) + EPS_);
    #pragma unroll
    for (int r=0;r<2;r++){
        int d = tid + r*256;
        ybf[(size_t)row*DI + d] = f2bu(g[r]*rinv*rw[d]);
    }
}

__global__ __launch_bounds__(256) void k_ln(const float* __restrict__ h,
                                            const float* __restrict__ lw,
                                            const float* __restrict__ lb,
                                            float* __restrict__ out){
    __shared__ float red[4];
    int row = blockIdx.x;
    int tid = threadIdx.x;
    float v = h[(size_t)row*DM + tid];
    float mu = blockSum256(v, red)*(1.f/256.f);
    float d = v - mu;
    float var = blockSum256(d*d, red)*(1.f/256.f);
    out[(size_t)row*DM + tid] = d*rsqrtf(var + EPS_)*lw[tid] + lb[tid];
}

__global__ __launch_bounds__(256) void k_meanl(const float* __restrict__ ln,
                                               float* __restrict__ hmp,
                                               int b0){
    int g = blockIdx.x, bl = blockIdx.y;
    int tid = threadIdx.x;
    float s = 0.f;
    for (int i=0;i<128;i++){
        int l = g*128 + i;
        s += ln[(size_t)(bl*L_ + l)*DM + tid];
    }
    hmp[((size_t)(b0+bl)*16 + g)*DM + tid] = s*(1.f/2048.f);
}

__global__ __launch_bounds__(256) void k_heads(const float* __restrict__ hmp,
                                               const float* __restrict__ dw,
                                               const float* __restrict__ db,
                                               const float* __restrict__ rw,
                                               const float* __restrict__ rb,
                                               float* __restrict__ out){
    __shared__ float red[4];
    int b = blockIdx.x;
    int tid = threadIdx.x;
    float hv = 0.f;
    #pragma unroll
    for (int g=0; g<16; g++) hv += hmp[((size_t)b*16 + g)*DM + tid];
    float s0 = hv*dw[tid];
    float s1 = hv*rw[tid*3+0];
    float s2 = hv*rw[tid*3+1];
    float s3 = hv*rw[tid*3+2];
    s0 = blockSum256(s0, red);
    s1 = blockSum256(s1, red);
    s2 = blockSum256(s2, red);
    s3 = blockSum256(s3, red);
    if (tid == 0){
        out[b] = s0 + db[0];
        out[16 + b*3 + 0] = s1 + rb[0];
        out[16 + b*3 + 1] = s2 + rb[1];
        out[16 + b*3 + 2] = s3 + rb[2];
    }
}

extern "C" void kernel_launch(void* const* d_in, const int* in_sizes, int n_in,
                              void* d_out, int out_size, void* d_ws, size_t ws_size,
                              hipStream_t stream){
    static const int expSizes[NIN] = {1507328,11776,256,1187840,10240,2560,32,32,32,2048,524288,256,256,256,1,768,3};
    float* out = (float*)d_out;

    if (n_in != NIN){
        k_sentinel<<<1,64,0,stream>>>(out, 9.0e6f);
        return;
    }
    for (int i=0;i<NIN;i++){
        if (in_sizes[i] != expSizes[i]){
            k_sentinel<<<1,64,0,stream>>>(out, (float)(i+1)*1.0e5f);
            return;
        }
    }
    size_t need16 = ((size_t)SLICEOFF + 2048ull*PERROW)*4ull;
    if (ws_size < need16){
        float mb = (float)(ws_size >> 20);
        k_sentinel<<<1,64,0,stream>>>(out, 2.0e7f + mb*131072.f);
        return;
    }

    float* ws = (float*)d_ws;
    int* flags = (int*)d_ws;
    float* stg = ws + STGOFF;
    unsigned short* ipwT = (unsigned short*)(ws + WIPT);
    unsigned short* opwT = (unsigned short*)(ws + WOPT);
    float* hmp = ws + HMPOFF;

    PtrTab pt;
    for (int i=0;i<NIN;i++) pt.p[i] = d_in[i];

    k_detect<<<NIN, 256, 0, stream>>>(pt, flags);
    k_stage<<<dim3(8, NSMALL), 256, 0, stream>>>(pt, flags, stg);
    k_wip<<<dim3(NP, NL), 256, 0, stream>>>(d_in[3], flags+3, ipwT);
    k_wop<<<dim3(DM, NL), 256, 0, stream>>>(d_in[10], flags+10, opwT);

    const float* inp_w = stg + 0;
    const float* inp_b = stg + 11776;
    const float* cw    = stg + 12032;
    const float* cb    = stg + 22272;
    const float* dtb   = stg + 24832;
    const float* alog  = stg + 24864;
    const float* Dp    = stg + 24896;
    const float* rmsw  = stg + 24928;
    const float* lnw   = stg + 26976;
    const float* lnb   = stg + 27232;
    const float* dw    = stg + 27488;
    const float* db    = stg + 27744;
    const float* rw    = stg + 27748;
    const float* rb    = stg + 28516;

    int nsl = 1;
    while (((size_t)SLICEOFF + ((size_t)MROWS/nsl)*PERROW)*4ull > ws_size) nsl <<= 1;
    const size_t R = (size_t)MROWS / nsl;
    const int SB = B_ / nsl;

    float* base = ws + SLICEOFF;
    float* hbuf = base;                                         // R*256 f32
    unsigned short* hbf  = (unsigned short*)(base + R*256);     // R*256 bf16
    unsigned short* zb   = (unsigned short*)(base + R*384);     // R*512 bf16
    unsigned short* xbb  = (unsigned short*)(base + R*640);     // R*648 bf16; y aliases
    unsigned short* ybB  = xbb;
    unsigned short* xcb  = (unsigned short*)(base + R*964);     // R*640 bf16
    float* S   = base + R*1284;                                 // R*512 f32 (also LN scratch)
    float* dt  = base + R*1796;                                 // R*8
    float* cum = base + R*1804;                                 // R*8
    unsigned short* ybf = (unsigned short*)(base + R*1812);     // R*512 bf16

    for (int sl=0; sl<nsl; sl++){
        k_inproj<<<(int)R, 256, 0, stream>>>(d_in[0], flags, (size_t)sl*R*46, inp_w, inp_b, hbuf, hbf);
        for (int li=0; li<NL; li++){
            k_mgemm<0><<<dim3(NP/128, R/128), 256, 0, stream>>>(
                hbf, ipwT + (size_t)li*NP*DM, hbuf, zb, xbb, ybf, DM);
            k_conv<<<2048, 256, 0, stream>>>(xbb, cw + li*CD*4, cb + li*CD, xcb, (int)(R*160));
            k_dtcum<<<dim3(NCH,NH,SB), 64, 0, stream>>>(xbb, dtb + li*NH, alog + li*NH, dt, cum);
            k_passS<<<dim3(NCH,NH,SB), 256, 0, stream>>>(xcb, dt, cum, S);
            k_combine<<<dim3(NH,SB), 256, 0, stream>>>(cum, S);
            k_finalize2<<<dim3(NCH,NH,SB), 256, 0, stream>>>(xcb, dt, cum, Dp + li*NH, S, ybB);
            k_gaterms<<<(int)R, 256, 0, stream>>>(zb, rmsw + li*DI, ybB, ybf);
            k_mgemm<1><<<dim3(DM/128, R/128), 256, 0, stream>>>(
                ybf, opwT + (size_t)li*DM*DI, hbuf, zb, xbb, hbf, DI);
        }
        k_ln<<<(int)R, 256, 0, stream>>>(hbuf, lnw, lnb, S);
        k_meanl<<<dim3(16,SB), 256, 0, stream>>>(S, hmp, sl*SB);
    }
    k_heads<<<B_, 256, 0, stream>>>(hmp, dw, db, rw, rb, out);
}

// Round 16
// 1422.882 us; speedup vs baseline: 1.4389x; 1.4360x over previous
//
#include <hip/hip_runtime.h>
#include <hip/hip_bf16.h>
#include <math.h>

typedef __hip_bfloat16 bf16;

#define B_ 16
#define L_ 2048
#define DM 256
#define DI 512
#define NH 8
#define HD 64
#define DS 64
#define CD 640
#define DIP 1160
#define XB 648
#define NP 1280
#define NL 4
#define Q_ 64
#define NCH 32
#define MROWS (B_*L_)
#define EPS_ 1e-5f
#define NIN 17
#define NSMALL 14
#define STGOFF 32
#define WIPT 28552
#define WOPT 683912
#define HMPOFF 946056
#define SLICEOFF 1011592
#define PERROW 2004

__device__ __forceinline__ float u2f(unsigned short u){ return __uint_as_float(((unsigned)u)<<16); }
__device__ __forceinline__ unsigned short f2bu(float f){ bf16 h = __float2bfloat16(f); return *(unsigned short*)&h; }
__device__ __forceinline__ float sigmoidf_(float x){ return 1.f/(1.f+expf(-x)); }
__device__ __forceinline__ float siluf_(float x){ return x*sigmoidf_(x); }
__device__ __forceinline__ float softplusf_(float x){ return (x>20.f)? x : log1pf(expf(x)); }

typedef __attribute__((ext_vector_type(8))) short short8v;
typedef __attribute__((ext_vector_type(4))) float float4v;

__device__ const int kN17[NIN] = {1507328,11776,256,1187840,10240,2560,32,32,32,2048,524288,256,256,256,1,768,3};
__device__ const int sIdx[NSMALL] = {1,2,4,5,6,7,8,9,11,12,13,14,15,16};
__device__ const int sNum[NSMALL] = {11776,256,10240,2560,32,32,32,2048,256,256,256,1,768,3};
__device__ const int sOff[NSMALL] = {0,11776,12032,22272,24832,24864,24896,24928,26976,27232,27488,27744,27748,28516};

struct PtrTab { const void* p[NIN]; };

__global__ __launch_bounds__(64) void k_sentinel(float* out, float v){
    int t = threadIdx.x;
    out[t] = (t==0) ? v : 0.f;
}

__global__ __launch_bounds__(256) void k_detect(PtrTab t, int* flags){
    int i = blockIdx.x;
    int n = kN17[i];
    int S = n < 4096 ? n : 4096;
    const unsigned short* u = (const unsigned short*)t.p[i];
    __shared__ int big, ze, zo, so;
    if (threadIdx.x == 0){ big=0; ze=0; zo=0; so=0; }
    __syncthreads();
    int lbig=0, lze=0, lzo=0, lso=0;
    for (int j=threadIdx.x; j<S; j+=256){
        unsigned short v = u[j];
        int e = (v>>7)&0xFF;
        if (e >= 131) lbig = 1;
        int isz = ((v & 0x7FFF) == 0) ? 1 : 0;
        if (j & 1){ lso++; lzo += isz; } else { lze += isz; }
    }
    if (lbig) atomicOr(&big, 1);
    atomicAdd(&ze, lze); atomicAdd(&zo, lzo); atomicAdd(&so, lso);
    __syncthreads();
    if (threadIdx.x == 0){
        int Se = S - so;
        flags[i] = (big || (so > 0 && 4*ze >= 3*Se && 4*zo <= so)) ? 1 : 0;
    }
}

__global__ __launch_bounds__(256) void k_stage(PtrTab t, const int* __restrict__ flags,
                                               float* __restrict__ stg){
    int a = blockIdx.y;
    int idx = sIdx[a];
    int n = sNum[a];
    float* dst = stg + sOff[a];
    const void* p = t.p[idx];
    if (flags[idx]){
        const float* s = (const float*)p;
        for (int j=blockIdx.x*256+threadIdx.x; j<n; j += gridDim.x*256) dst[j] = s[j];
    } else {
        const unsigned short* s = (const unsigned short*)p;
        for (int j=blockIdx.x*256+threadIdx.x; j<n; j += gridDim.x*256) dst[j] = u2f(s[j]);
    }
}

__global__ __launch_bounds__(256) void k_wip(const void* __restrict__ src,
                                             const int* __restrict__ flag,
                                             unsigned short* __restrict__ dst){
    int n = blockIdx.x, l = blockIdx.y, k = threadIdx.x;
    unsigned short b = 0;
    if (n < DIP){
        size_t si = ((size_t)l*DM + k)*DIP + n;
        if (flag[0]) b = f2bu(((const float*)src)[si]);
        else         b = ((const unsigned short*)src)[si];
    }
    dst[((size_t)l*NP + n)*DM + k] = b;
}

__global__ __launch_bounds__(256) void k_wop(const void* __restrict__ src,
                                             const int* __restrict__ flag,
                                             unsigned short* __restrict__ dst){
    int n = blockIdx.x, l = blockIdx.y;
    for (int k = threadIdx.x; k < DI; k += 256){
        size_t si = ((size_t)l*DI + k)*DM + n;
        unsigned short b;
        if (flag[0]) b = f2bu(((const float*)src)[si]);
        else         b = ((const unsigned short*)src)[si];
        dst[((size_t)l*DM + n)*DI + k] = b;
    }
}

__device__ __forceinline__ float blockSum256(float v, float* red){
    #pragma unroll
    for (int off=32; off>0; off>>=1) v += __shfl_down(v, off);
    if ((threadIdx.x & 63) == 0) red[threadIdx.x >> 6] = v;
    __syncthreads();
    float s = red[0] + red[1] + red[2] + red[3];
    __syncthreads();
    return s;
}

__global__ __launch_bounds__(256) void k_inproj(const void* __restrict__ x,
                                                const int* __restrict__ flags,
                                                size_t xoff,
                                                const float* __restrict__ w,
                                                const float* __restrict__ bias,
                                                float* __restrict__ h,
                                                unsigned short* __restrict__ hbf){
    __shared__ float xs[46];
    int row = blockIdx.x;
    int t = threadIdx.x;
    bool f32 = flags[0] != 0;
    if (t < 46){
        size_t j = xoff + (size_t)row*46 + t;
        xs[t] = f32 ? ((const float*)x)[j] : u2f(((const unsigned short*)x)[j]);
    }
    __syncthreads();
    float acc = bias[t];
    #pragma unroll 2
    for (int k=0;k<46;k++) acc += xs[k]*w[k*DM + t];
    h[(size_t)row*DM + t] = acc;
    hbf[(size_t)row*DM + t] = f2bu(acc);
}

template<int MODE>
__global__ __launch_bounds__(256) void k_mgemm(const unsigned short* __restrict__ A,
                                               const unsigned short* __restrict__ Bt,
                                               float* __restrict__ O1,
                                               unsigned short* __restrict__ O1b,
                                               unsigned short* __restrict__ O2b,
                                               unsigned short* __restrict__ O3,
                                               int K){
    __shared__ unsigned short As[128*40];
    __shared__ unsigned short Bs[128*40];
    int tid = threadIdx.x;
    int wave = tid >> 6, lane = tid & 63, quad = lane >> 4, l15 = lane & 15;
    int mbase = blockIdx.y*128, nbase = blockIdx.x*128;
    int wm = (wave & 1)*64, wn = (wave >> 1)*64;
    float4v zero4 = {0.f,0.f,0.f,0.f};
    float4v acc[4][4];
    #pragma unroll
    for (int mi=0;mi<4;mi++)
        #pragma unroll
        for (int ni=0;ni<4;ni++) acc[mi][ni] = zero4;
    for (int k0 = 0; k0 < K; k0 += 32){
        #pragma unroll
        for (int i=0;i<2;i++){
            int c = tid + i*256;
            int row = c >> 2, koff = (c & 3)*8;
            *(uint4*)&As[row*40 + koff] = *(const uint4*)&A[(size_t)(mbase+row)*K + k0 + koff];
            *(uint4*)&Bs[row*40 + koff] = *(const uint4*)&Bt[(size_t)(nbase+row)*K + k0 + koff];
        }
        __syncthreads();
        short8v af[4], bfr[4];
        #pragma unroll
        for (int mi=0;mi<4;mi++) af[mi] = *(const short8v*)&As[(wm + mi*16 + l15)*40 + quad*8];
        #pragma unroll
        for (int ni=0;ni<4;ni++) bfr[ni] = *(const short8v*)&Bs[(wn + ni*16 + l15)*40 + quad*8];
        #pragma unroll
        for (int mi=0;mi<4;mi++)
            #pragma unroll
            for (int ni=0;ni<4;ni++)
                acc[mi][ni] = __builtin_amdgcn_mfma_f32_16x16x32_bf16(af[mi], bfr[ni], acc[mi][ni], 0, 0, 0);
        __syncthreads();
    }
    #pragma unroll
    for (int mi=0;mi<4;mi++){
        #pragma unroll
        for (int ni=0;ni<4;ni++){
            int col = nbase + wn + ni*16 + l15;
            #pragma unroll
            for (int reg=0;reg<4;reg++){
                int grow = mbase + wm + mi*16 + quad*4 + reg;
                float v = acc[mi][ni][reg];
                if (MODE == 0){
                    if (col < DI) O1b[(size_t)grow*DI + col] = f2bu(v);
                    else if (col < DIP) O2b[(size_t)grow*XB + (col - DI)] = f2bu(v);
                } else {
                    float hnew = O1[(size_t)grow*DM + col] + v;
                    O1[(size_t)grow*DM + col] = hnew;
                    O3[(size_t)grow*DM + col] = f2bu(hnew);
                }
            }
        }
    }
}

__global__ __launch_bounds__(64) void k_dtcum(const unsigned short* __restrict__ xb,
                                              const float* __restrict__ dtb,
                                              const float* __restrict__ alog,
                                              float* __restrict__ dto,
                                              float* __restrict__ cumo){
    int kk = blockIdx.x, h = blockIdx.y, b = blockIdx.z;
    int t = threadIdx.x;
    int l = kk*Q_ + t;
    float raw = u2f(xb[(size_t)(b*L_ + l)*XB + CD + h]);
    float dtv = softplusf_(raw + dtb[h]);
    float A = -expf(alog[h]);
    float s = dtv * A;
    #pragma unroll
    for (int off=1; off<64; off<<=1){
        float u = __shfl_up(s, off);
        if (t >= off) s += u;
    }
    int base = (b*NH + h)*L_ + l;
    dto[base] = dtv;
    cumo[base] = s;
}

// ------- passS with FUSED conv+SiLU (reads raw xbb) -------
__global__ __launch_bounds__(256) void k_passS(const unsigned short* __restrict__ xbb,
                                               const float* __restrict__ cw,
                                               const float* __restrict__ cb,
                                               const float* __restrict__ dt,
                                               const float* __restrict__ cum,
                                               float* __restrict__ S){
    __shared__ unsigned short Bw[64*72];
    __shared__ unsigned short Xt[64*72];
    __shared__ float sw[64];
    __shared__ float wt[2*64*5];   // [grp(B=0,X=1)][ch][tap0..3,bias]
    int kk = blockIdx.x, h = blockIdx.y, b = blockIdx.z;
    int tid = threadIdx.x;
    int bh = b*NH + h;
    int l0 = kk*Q_;
    if (tid < 64){
        int base = bh*L_ + l0;
        float c = cum[base + tid];
        float c63 = cum[base + 63];
        sw[tid] = dt[base + tid]*expf(fminf(c63 - c, 0.f));
    }
    if (tid < 128){
        int grp = tid >> 6, ch = tid & 63;
        int gc = (grp == 0) ? (DI + ch) : (h*HD + ch);
        #pragma unroll
        for (int j=0;j<4;j++) wt[(grp*64 + ch)*5 + j] = cw[gc*4 + j];
        wt[(grp*64 + ch)*5 + 4] = cb[gc];
    }
    __syncthreads();
    int srow = tid >> 4, c0 = (tid & 15)*4;
    #pragma unroll
    for (int i=0;i<4;i++){
        int s = srow + i*16;
        int lg = l0 + s;
        float aB[4], aX[4];
        #pragma unroll
        for (int q=0;q<4;q++){
            aB[q] = wt[(c0+q)*5 + 4];
            aX[q] = wt[(64+c0+q)*5 + 4];
        }
        #pragma unroll
        for (int j=0;j<4;j++){
            int l2 = lg - 3 + j;
            if (l2 >= 0){
                size_t rb = ((size_t)b*L_ + l2)*XB;
                ushort4 bv = *(const ushort4*)&xbb[rb + DI + c0];
                ushort4 xv = *(const ushort4*)&xbb[rb + h*HD + c0];
                aB[0] += u2f(bv.x)*wt[(c0+0)*5+j];
                aB[1] += u2f(bv.y)*wt[(c0+1)*5+j];
                aB[2] += u2f(bv.z)*wt[(c0+2)*5+j];
                aB[3] += u2f(bv.w)*wt[(c0+3)*5+j];
                aX[0] += u2f(xv.x)*wt[(64+c0+0)*5+j];
                aX[1] += u2f(xv.y)*wt[(64+c0+1)*5+j];
                aX[2] += u2f(xv.z)*wt[(64+c0+2)*5+j];
                aX[3] += u2f(xv.w)*wt[(64+c0+3)*5+j];
            }
        }
        float w = sw[s];
        #pragma unroll
        for (int q=0;q<4;q++){
            Bw[(c0+q)*72 + s] = f2bu(w*siluf_(aB[q]));
            Xt[(c0+q)*72 + s] = f2bu(siluf_(aX[q]));
        }
    }
    __syncthreads();
    int wave = tid >> 6, lane = tid & 63, quad = lane >> 4, l15 = lane & 15;
    int wn = (wave & 1)*32, wp = (wave >> 1)*32;
    float4v zero4 = {0.f,0.f,0.f,0.f};
    float4v acc[2][2];
    #pragma unroll
    for (int mi=0;mi<2;mi++)
        #pragma unroll
        for (int ni=0;ni<2;ni++) acc[mi][ni] = zero4;
    #pragma unroll
    for (int k0=0;k0<64;k0+=32){
        short8v af[2], bfr[2];
        #pragma unroll
        for (int mi=0;mi<2;mi++) af[mi] = *(const short8v*)&Bw[(wn + mi*16 + l15)*72 + k0 + quad*8];
        #pragma unroll
        for (int ni=0;ni<2;ni++) bfr[ni] = *(const short8v*)&Xt[(wp + ni*16 + l15)*72 + k0 + quad*8];
        #pragma unroll
        for (int mi=0;mi<2;mi++)
            #pragma unroll
            for (int ni=0;ni<2;ni++)
                acc[mi][ni] = __builtin_amdgcn_mfma_f32_16x16x32_bf16(af[mi], bfr[ni], acc[mi][ni], 0, 0, 0);
    }
    size_t Sbase = ((size_t)bh*NCH + kk)*4096;
    #pragma unroll
    for (int mi=0;mi<2;mi++){
        #pragma unroll
        for (int ni=0;ni<2;ni++){
            int p = wp + ni*16 + l15;
            #pragma unroll
            for (int reg=0;reg<4;reg++){
                int n = wn + mi*16 + quad*4 + reg;
                S[Sbase + n*64 + p] = acc[mi][ni][reg];
            }
        }
    }
}

__global__ __launch_bounds__(256) void k_combine(const float* __restrict__ cum,
                                                 float* __restrict__ S){
    int h = blockIdx.x, b = blockIdx.y;
    int bh = b*NH + h;
    int tid = threadIdx.x;
    float4 st[4];
    #pragma unroll
    for (int i=0;i<4;i++) st[i] = make_float4(0.f,0.f,0.f,0.f);
    size_t base0 = ((size_t)bh*NCH)*4096 + (size_t)tid*16;
    for (int k=0;k<NCH;k++){
        size_t base = base0 + (size_t)k*4096;
        float dk = expf(fminf(cum[bh*L_ + k*Q_ + 63], 0.f));
        float4 a[4];
        #pragma unroll
        for (int i=0;i<4;i++) a[i] = *(const float4*)&S[base + i*4];
        #pragma unroll
        for (int i=0;i<4;i++) *(float4*)&S[base + i*4] = st[i];
        #pragma unroll
        for (int i=0;i<4;i++){
            st[i].x = a[i].x + dk*st[i].x;
            st[i].y = a[i].y + dk*st[i].y;
            st[i].z = a[i].z + dk*st[i].z;
            st[i].w = a[i].w + dk*st[i].w;
        }
    }
}

// ------- finalize2 with FUSED conv+SiLU (reads raw xbb), writes y (bf16, own buffer) -------
__global__ __launch_bounds__(256) void k_finalize2(const unsigned short* __restrict__ xbb,
                                                   const float* __restrict__ cw,
                                                   const float* __restrict__ cb,
                                                   const float* __restrict__ dt,
                                                   const float* __restrict__ cum,
                                                   const float* __restrict__ Dp,
                                                   const float* __restrict__ S,
                                                   unsigned short* __restrict__ yB){
    __shared__ unsigned short Ct[64*72];
    __shared__ unsigned short Bs[64*72];
    __shared__ unsigned short Xt[64*72];
    __shared__ unsigned short St[64*72];
    __shared__ unsigned short Ml[64*72];
    __shared__ float sdt[64], scum[64];
    __shared__ float wt[3*64*5];   // [grp(C=0,B=1,X=2)][ch][tap0..3,bias]
    int kk = blockIdx.x, h = blockIdx.y, b = blockIdx.z;
    int tid = threadIdx.x;
    int bh = b*NH + h;
    int l0 = kk*Q_;
    if (tid < 64){
        int base = bh*L_ + l0;
        sdt[tid] = dt[base + tid];
        scum[tid] = cum[base + tid];
    }
    if (tid < 192){
        int grp = tid / 64, ch = tid & 63;
        int gc = (grp == 0) ? (DI + DS + ch) : (grp == 1) ? (DI + ch) : (h*HD + ch);
        #pragma unroll
        for (int j=0;j<4;j++) wt[(grp*64 + ch)*5 + j] = cw[gc*4 + j];
        wt[(grp*64 + ch)*5 + 4] = cb[gc];
    }
    __syncthreads();
    int rr = tid >> 4, c0 = (tid & 15)*4;
    size_t Sbase = ((size_t)bh*NCH + kk)*4096;
    #pragma unroll
    for (int i=0;i<4;i++){
        int r = rr + i*16;
        int lg = l0 + r;
        float aC[4], aB[4], aX[4];
        #pragma unroll
        for (int q=0;q<4;q++){
            aC[q] = wt[(c0+q)*5 + 4];
            aB[q] = wt[(64+c0+q)*5 + 4];
            aX[q] = wt[(128+c0+q)*5 + 4];
        }
        #pragma unroll
        for (int j=0;j<4;j++){
            int l2 = lg - 3 + j;
            if (l2 >= 0){
                size_t rb = ((size_t)b*L_ + l2)*XB;
                ushort4 cv = *(const ushort4*)&xbb[rb + DI + DS + c0];
                ushort4 bv = *(const ushort4*)&xbb[rb + DI + c0];
                ushort4 xv = *(const ushort4*)&xbb[rb + h*HD + c0];
                aC[0] += u2f(cv.x)*wt[(c0+0)*5+j];
                aC[1] += u2f(cv.y)*wt[(c0+1)*5+j];
                aC[2] += u2f(cv.z)*wt[(c0+2)*5+j];
                aC[3] += u2f(cv.w)*wt[(c0+3)*5+j];
                aB[0] += u2f(bv.x)*wt[(64+c0+0)*5+j];
                aB[1] += u2f(bv.y)*wt[(64+c0+1)*5+j];
                aB[2] += u2f(bv.z)*wt[(64+c0+2)*5+j];
                aB[3] += u2f(bv.w)*wt[(64+c0+3)*5+j];
                aX[0] += u2f(xv.x)*wt[(128+c0+0)*5+j];
                aX[1] += u2f(xv.y)*wt[(128+c0+1)*5+j];
                aX[2] += u2f(xv.z)*wt[(128+c0+2)*5+j];
                aX[3] += u2f(xv.w)*wt[(128+c0+3)*5+j];
            }
        }
        #pragma unroll
        for (int q=0;q<4;q++){
            Ct[r*72 + c0+q] = f2bu(siluf_(aC[q]));
            Bs[r*72 + c0+q] = f2bu(siluf_(aB[q]));
            Xt[(c0+q)*72 + r] = f2bu(siluf_(aX[q]));
        }
        float4 sv = *(const float4*)&S[Sbase + r*64 + c0];
        St[(c0+0)*72 + r] = f2bu(sv.x);
        St[(c0+1)*72 + r] = f2bu(sv.y);
        St[(c0+2)*72 + r] = f2bu(sv.z);
        St[(c0+3)*72 + r] = f2bu(sv.w);
    }
    __syncthreads();
    int wave = tid >> 6, lane = tid & 63, quad = lane >> 4, l15 = lane & 15;
    int wt2 = (wave & 1)*32, wc = (wave >> 1)*32;
    float4v zero4 = {0.f,0.f,0.f,0.f};
    {
        float4v acc[2][2];
        #pragma unroll
        for (int mi=0;mi<2;mi++)
            #pragma unroll
            for (int ni=0;ni<2;ni++) acc[mi][ni] = zero4;
        #pragma unroll
        for (int k0=0;k0<64;k0+=32){
            short8v af[2], bfr[2];
            #pragma unroll
            for (int mi=0;mi<2;mi++) af[mi] = *(const short8v*)&Ct[(wt2 + mi*16 + l15)*72 + k0 + quad*8];
            #pragma unroll
            for (int ni=0;ni<2;ni++) bfr[ni] = *(const short8v*)&Bs[(wc + ni*16 + l15)*72 + k0 + quad*8];
            #pragma unroll
            for (int mi=0;mi<2;mi++)
                #pragma unroll
                for (int ni=0;ni<2;ni++)
                    acc[mi][ni] = __builtin_amdgcn_mfma_f32_16x16x32_bf16(af[mi], bfr[ni], acc[mi][ni], 0, 0, 0);
        }
        #pragma unroll
        for (int mi=0;mi<2;mi++){
            #pragma unroll
            for (int ni=0;ni<2;ni++){
                int s = wc + ni*16 + l15;
                #pragma unroll
                for (int reg=0;reg<4;reg++){
                    int t = wt2 + mi*16 + quad*4 + reg;
                    float m = (s <= t) ? acc[mi][ni][reg]*sdt[s]*expf(fminf(scum[t]-scum[s], 0.f)) : 0.f;
                    Ml[t*72 + s] = f2bu(m);
                }
            }
        }
    }
    __syncthreads();
    {
        float4v a1[2][2], a2[2][2];
        #pragma unroll
        for (int mi=0;mi<2;mi++)
            #pragma unroll
            for (int ni=0;ni<2;ni++){ a1[mi][ni] = zero4; a2[mi][ni] = zero4; }
        #pragma unroll
        for (int k0=0;k0<64;k0+=32){
            short8v mf[2], cf[2], xf[2], sf[2];
            #pragma unroll
            for (int mi=0;mi<2;mi++){
                mf[mi] = *(const short8v*)&Ml[(wt2 + mi*16 + l15)*72 + k0 + quad*8];
                cf[mi] = *(const short8v*)&Ct[(wt2 + mi*16 + l15)*72 + k0 + quad*8];
            }
            #pragma unroll
            for (int ni=0;ni<2;ni++){
                xf[ni] = *(const short8v*)&Xt[(wc + ni*16 + l15)*72 + k0 + quad*8];
                sf[ni] = *(const short8v*)&St[(wc + ni*16 + l15)*72 + k0 + quad*8];
            }
            #pragma unroll
            for (int mi=0;mi<2;mi++)
                #pragma unroll
                for (int ni=0;ni<2;ni++){
                    a1[mi][ni] = __builtin_amdgcn_mfma_f32_16x16x32_bf16(mf[mi], xf[ni], a1[mi][ni], 0, 0, 0);
                    a2[mi][ni] = __builtin_amdgcn_mfma_f32_16x16x32_bf16(cf[mi], sf[ni], a2[mi][ni], 0, 0, 0);
                }
        }
        float Dh = Dp[h];
        #pragma unroll
        for (int mi=0;mi<2;mi++){
            #pragma unroll
            for (int ni=0;ni<2;ni++){
                int p = wc + ni*16 + l15;
                #pragma unroll
                for (int reg=0;reg<4;reg++){
                    int t = wt2 + mi*16 + quad*4 + reg;
                    float e = expf(fminf(scum[t], 0.f));
                    float xval = u2f(Xt[p*72 + t]);
                    yB[(size_t)(b*L_ + l0 + t)*DI + h*HD + p] =
                        f2bu(a1[mi][ni][reg] + e*a2[mi][ni][reg] + Dh*xval);
                }
            }
        }
    }
}

__global__ __launch_bounds__(256) void k_gaterms(const unsigned short* __restrict__ z,
                                                 const float* __restrict__ rw,
                                                 const unsigned short* __restrict__ yB,
                                                 unsigned short* __restrict__ ybf){
    __shared__ float red[4];
    int row = blockIdx.x;
    int tid = threadIdx.x;
    float g[2]; float ss = 0.f;
    #pragma unroll
    for (int r=0;r<2;r++){
        int d = tid + r*256;
        float zv = u2f(z[(size_t)row*DI + d]);
        float yv = u2f(yB[(size_t)row*DI + d]);
        float gv = yv * siluf_(zv);
        g[r] = gv;
        ss += gv*gv;
    }
    float tot = blockSum256(ss, red);
    float rinv = rsqrtf(tot*(1.f/512.f) + EPS_);
    #pragma unroll
    for (int r=0;r<2;r++){
        int d = tid + r*256;
        ybf[(size_t)row*DI + d] = f2bu(g[r]*rinv*rw[d]);
    }
}

__global__ __launch_bounds__(256) void k_ln(const float* __restrict__ h,
                                            const float* __restrict__ lw,
                                            const float* __restrict__ lb,
                                            float* __restrict__ out){
    __shared__ float red[4];
    int row = blockIdx.x;
    int tid = threadIdx.x;
    float v = h[(size_t)row*DM + tid];
    float mu = blockSum256(v, red)*(1.f/256.f);
    float d = v - mu;
    float var = blockSum256(d*d, red)*(1.f/256.f);
    out[(size_t)row*DM + tid] = d*rsqrtf(var + EPS_)*lw[tid] + lb[tid];
}

__global__ __launch_bounds__(256) void k_meanl(const float* __restrict__ ln,
                                               float* __restrict__ hmp,
                                               int b0){
    int g = blockIdx.x, bl = blockIdx.y;
    int tid = threadIdx.x;
    float s = 0.f;
    for (int i=0;i<128;i++){
        int l = g*128 + i;
        s += ln[(size_t)(bl*L_ + l)*DM + tid];
    }
    hmp[((size_t)(b0+bl)*16 + g)*DM + tid] = s*(1.f/2048.f);
}

__global__ __launch_bounds__(256) void k_heads(const float* __restrict__ hmp,
                                               const float* __restrict__ dw,
                                               const float* __restrict__ db,
                                               const float* __restrict__ rw,
                                               const float* __restrict__ rb,
                                               float* __restrict__ out){
    __shared__ float red[4];
    int b = blockIdx.x;
    int tid = threadIdx.x;
    float hv = 0.f;
    #pragma unroll
    for (int g=0; g<16; g++) hv += hmp[((size_t)b*16 + g)*DM + tid];
    float s0 = hv*dw[tid];
    float s1 = hv*rw[tid*3+0];
    float s2 = hv*rw[tid*3+1];
    float s3 = hv*rw[tid*3+2];
    s0 = blockSum256(s0, red);
    s1 = blockSum256(s1, red);
    s2 = blockSum256(s2, red);
    s3 = blockSum256(s3, red);
    if (tid == 0){
        out[b] = s0 + db[0];
        out[16 + b*3 + 0] = s1 + rb[0];
        out[16 + b*3 + 1] = s2 + rb[1];
        out[16 + b*3 + 2] = s3 + rb[2];
    }
}

extern "C" void kernel_launch(void* const* d_in, const int* in_sizes, int n_in,
                              void* d_out, int out_size, void* d_ws, size_t ws_size,
                              hipStream_t stream){
    static const int expSizes[NIN] = {1507328,11776,256,1187840,10240,2560,32,32,32,2048,524288,256,256,256,1,768,3};
    float* out = (float*)d_out;

    if (n_in != NIN){
        k_sentinel<<<1,64,0,stream>>>(out, 9.0e6f);
        return;
    }
    for (int i=0;i<NIN;i++){
        if (in_sizes[i] != expSizes[i]){
            k_sentinel<<<1,64,0,stream>>>(out, (float)(i+1)*1.0e5f);
            return;
        }
    }
    size_t need16 = ((size_t)SLICEOFF + 2048ull*PERROW)*4ull;
    if (ws_size < need16){
        float mb = (float)(ws_size >> 20);
        k_sentinel<<<1,64,0,stream>>>(out, 2.0e7f + mb*131072.f);
        return;
    }

    float* ws = (float*)d_ws;
    int* flags = (int*)d_ws;
    float* stg = ws + STGOFF;
    unsigned short* ipwT = (unsigned short*)(ws + WIPT);
    unsigned short* opwT = (unsigned short*)(ws + WOPT);
    float* hmp = ws + HMPOFF;

    PtrTab pt;
    for (int i=0;i<NIN;i++) pt.p[i] = d_in[i];

    k_detect<<<NIN, 256, 0, stream>>>(pt, flags);
    k_stage<<<dim3(8, NSMALL), 256, 0, stream>>>(pt, flags, stg);
    k_wip<<<dim3(NP, NL), 256, 0, stream>>>(d_in[3], flags+3, ipwT);
    k_wop<<<dim3(DM, NL), 256, 0, stream>>>(d_in[10], flags+10, opwT);

    const float* inp_w = stg + 0;
    const float* inp_b = stg + 11776;
    const float* cw    = stg + 12032;
    const float* cb    = stg + 22272;
    const float* dtb   = stg + 24832;
    const float* alog  = stg + 24864;
    const float* Dp    = stg + 24896;
    const float* rmsw  = stg + 24928;
    const float* lnw   = stg + 26976;
    const float* lnb   = stg + 27232;
    const float* dw    = stg + 27488;
    const float* db    = stg + 27744;
    const float* rw    = stg + 27748;
    const float* rb    = stg + 28516;

    int nsl = 1;
    while (((size_t)SLICEOFF + ((size_t)MROWS/nsl)*PERROW)*4ull > ws_size) nsl <<= 1;
    const size_t R = (size_t)MROWS / nsl;
    const int SB = B_ / nsl;

    float* base = ws + SLICEOFF;
    float* hbuf = base;                                         // R*256 f32
    unsigned short* hbf  = (unsigned short*)(base + R*256);     // R*256 bf16
    unsigned short* zb   = (unsigned short*)(base + R*384);     // R*512 bf16
    unsigned short* xbb  = (unsigned short*)(base + R*640);     // R*648 bf16 (raw xBC+dt)
    unsigned short* ybB  = (unsigned short*)(base + R*964);     // R*512 bf16 (y, own buffer)
    float* S   = base + R*1220;                                 // R*512 f32 (also LN scratch)
    float* dt  = base + R*1732;                                 // R*8
    float* cum = base + R*1740;                                 // R*8
    unsigned short* ybf = (unsigned short*)(base + R*1748);     // R*512 bf16

    for (int sl=0; sl<nsl; sl++){
        k_inproj<<<(int)R, 256, 0, stream>>>(d_in[0], flags, (size_t)sl*R*46, inp_w, inp_b, hbuf, hbf);
        for (int li=0; li<NL; li++){
            const float* cwl = cw + li*CD*4;
            const float* cbl = cb + li*CD;
            k_mgemm<0><<<dim3(NP/128, R/128), 256, 0, stream>>>(
                hbf, ipwT + (size_t)li*NP*DM, hbuf, zb, xbb, ybf, DM);
            k_dtcum<<<dim3(NCH,NH,SB), 64, 0, stream>>>(xbb, dtb + li*NH, alog + li*NH, dt, cum);
            k_passS<<<dim3(NCH,NH,SB), 256, 0, stream>>>(xbb, cwl, cbl, dt, cum, S);
            k_combine<<<dim3(NH,SB), 256, 0, stream>>>(cum, S);
            k_finalize2<<<dim3(NCH,NH,SB), 256, 0, stream>>>(xbb, cwl, cbl, dt, cum, Dp + li*NH, S, ybB);
            k_gaterms<<<(int)R, 256, 0, stream>>>(zb, rmsw + li*DI, ybB, ybf);
            k_mgemm<1><<<dim3(DM/128, R/128), 256, 0, stream>>>(
                ybf, opwT + (size_t)li*DM*DI, hbuf, zb, xbb, hbf, DI);
        }
        k_ln<<<(int)R, 256, 0, stream>>>(hbuf, lnw, lnb, S);
        k_meanl<<<dim3(16,SB), 256, 0, stream>>>(S, hmp, sl*SB);
    }
    k_heads<<<B_, 256, 0, stream>>>(hmp, dw, db, rw, rb, out);
}